// Round 5
// baseline (267.476 us; speedup 1.0000x reference)
//
#include <hip/hip_runtime.h>
#include <hip/hip_bf16.h>

// Problem constants (from reference)
#define E_TOTAL 300000
#define N_NODES 50000
#define NDIM    128      // node feature dim
#define KDIM    256      // 2*NDIM = GEMM K
#define HDIM    512      // 2*HIDDEN = GEMM N (both MLP branches fused)
#define BN_EPS  1e-5f
#define NTILES  ((E_TOTAL + 63) / 64)   // 4688 tiles of 64 edges
#define NBLK    256                      // persistent blocks, 1/CU
#define NF_BLOCKS 6250                   // 50000*128/4 float4s / 256 threads

typedef __attribute__((ext_vector_type(8))) short bf16x8;
typedef __attribute__((ext_vector_type(16))) float f32x16;
typedef const __attribute__((address_space(1))) unsigned int* gas1_t;
typedef __attribute__((address_space(3))) unsigned int* las3_t;

__device__ __forceinline__ unsigned short f2bf(float f) {
  unsigned u = __float_as_uint(f);
  u += 0x7fffu + ((u >> 16) & 1u);   // round-to-nearest-even
  return (unsigned short)(u >> 16);
}

// ---- single fused prep kernel ----
// blocks [0, NF_BLOCKS): node_feat fp32 -> bf16 table
// blocks [NF_BLOCKS, NF_BLOCKS+16): W1 (BN-folded, roll-fused) -> 32x32 MFMA B-frag order
//   frag (ct,kt), ct in [0,16) (32 cols), kt in [0,16) (16 k):
//   lane holds B[k = kt*16 + (lane>>5)*8 + j][col = ct*32 + (lane&31)]
//   at Wswz[((ct*16+kt)*64 + lane)*8]. col>=256: roll branch uses W1[(k+16)&255].
// block NF_BLOCKS+16: folded bias (cbias) + 0.5*W2 (w2c)
__global__ void prep_kernel(const float* __restrict__ nf, unsigned short* __restrict__ nfb,
                            const float* __restrict__ W1, const float* __restrict__ b1,
                            const float* __restrict__ gamma, const float* __restrict__ beta,
                            const float* __restrict__ mean, const float* __restrict__ var,
                            const float* __restrict__ W2,
                            unsigned short* __restrict__ Wswz,
                            float* __restrict__ cbias, float* __restrict__ w2c) {
  int b = blockIdx.x;
  int tid = threadIdx.x;
  if (b < NF_BLOCKS) {
    int i = b * 256 + tid;                     // exactly 1.6M float4s
    float4 v = ((const float4*)nf)[i];
    ushort4 o;
    o.x = f2bf(v.x); o.y = f2bf(v.y); o.z = f2bf(v.z); o.w = f2bf(v.w);
    ((ushort4*)nfb)[i] = o;
  } else if (b < NF_BLOCKS + 16) {
    int ct   = b - NF_BLOCKS;
    int lane = tid & 63;
    int col  = ct * 32 + (lane & 31);
    int jj   = col & 255;
    int shift = (col >= 256) ? 16 : 0;
    float s = gamma[jj] * rsqrtf(var[jj] + BN_EPS);
    #pragma unroll
    for (int it = 0; it < 4; it++) {
      int kt = (tid >> 6) + it * 4;
      unsigned short o[8];
      #pragma unroll
      for (int j = 0; j < 8; j++) {
        int k  = kt * 16 + ((lane >> 5) << 3) + j;
        int ks = (k + shift) & 255;
        o[j] = f2bf(W1[ks * 256 + jj] * s);
      }
      *(uint4*)(Wswz + ((size_t)(ct * 16 + kt) * 64 + lane) * 8) = *(const uint4*)o;
    }
  } else {
    for (int j = tid; j < HDIM; j += 256) {
      int jj = j & 255;
      float s = gamma[jj] * rsqrtf(var[jj] + BN_EPS);
      cbias[j] = b1[jj] * s + beta[jj] - mean[jj] * s;
      w2c[j]  = 0.5f * W2[jj];                 // fold the 0.5 average here
    }
  }
}

// ---- main: persistent, 512 threads = 8 waves, 32x32x16 MFMA.
// Wave w owns cols [w*64, w*64+64) = 2 col-tiles of 32; B in registers (bq[2][16]).
// A staged per 64-edge tile via global_load_lds DMA into 32x32 A-frag order:
//   frag f = mt*16 + kt at Ab[buf][f*512 + lane*8] (shorts);
//   lane holds A[row = mt*32 + (lane&31)][k = kt*16 + (lane>>5)*8 + j].
// Each wave stages 4 frags: mt = w>>2, kt = (w&3)*4 + i  ->  ONE node index per wave per tile.
// kt loop manually software-pipelined (prefetch kt+1's A-frags before kt's MFMAs).
__global__ __launch_bounds__(512, 2) void edge_mlp_kernel(
    const unsigned short* __restrict__ nfb, const int* __restrict__ eidx,
    const unsigned short* __restrict__ Wswz, const float* __restrict__ cbias,
    const float* __restrict__ w2c, const float* __restrict__ b2,
    float* __restrict__ out) {
  __shared__ unsigned short Ab[2][32 * 512];   // 2 x 32KB
  __shared__ float partial[2][8][64];

  const int tid  = threadIdx.x;
  const int w    = tid >> 6;
  const int lane = tid & 63;
  const int l31  = lane & 31;
  const int lh   = lane >> 5;        // lane half

  // ---- B into registers (once): wave w -> ct in {w*2, w*2+1} ----
  const bf16x8* Wf = (const bf16x8*)Wswz;
  bf16x8 bq[2][16];
  #pragma unroll
  for (int n = 0; n < 2; n++)
    #pragma unroll
    for (int kt = 0; kt < 16; kt++)
      bq[n][kt] = Wf[((w * 2 + n) * 16 + kt) * 64 + lane];

  float cj[2], w2j[2];
  #pragma unroll
  for (int n = 0; n < 2; n++) {
    int j = (w * 2 + n) * 32 + l31;
    cj[n]  = cbias[j];
    w2j[n] = w2c[j];
  }
  const float b2v = b2[0];

  // staging role (wave-constant): frags f = fbase+i, i=0..3
  const int smt   = w >> 2;                // M-tile this wave stages
  const int shalf = (w >> 1) & 1;          // 0: row-node endpoint, 1: col-node
  const int kbase = (w & 1) * 4;           // feature chunk base (x16 shorts)
  const int fbase = smt * 16 + (w & 3) * 4;
  const int* eptr = eidx + shalf * E_TOTAL;

  int t = blockIdx.x;

  // node index for tile t (used now) and t+NBLK (prefetched)
  int e0 = t * 64 + smt * 32 + l31;
  if (e0 >= E_TOTAL) e0 = E_TOTAL - 1;
  int node0 = eptr[e0];
  int nn;
  {
    int tn = t + NBLK; if (tn >= NTILES) tn = NTILES - 1;
    int e1 = tn * 64 + smt * 32 + l31; if (e1 >= E_TOTAL) e1 = E_TOTAL - 1;
    nn = eptr[e1];
  }

  // ---- stage tile t into Ab[0] ----
  {
    const unsigned short* gbase = nfb + (size_t)node0 * NDIM + kbase * 16 + lh * 8;
    #pragma unroll
    for (int i = 0; i < 4; i++)
      __builtin_amdgcn_global_load_lds((gas1_t)(gbase + i * 16),
                                       (las3_t)(&Ab[0][(fbase + i) * 512]),
                                       16, 0, 0);
  }
  __syncthreads();

  int p = 0;
  for (; t < NTILES; t += NBLK) {
    // ---- stage tile t+NBLK into Ab[p^1] (indices already in nn) ----
    {
      const unsigned short* gbase = nfb + (size_t)nn * NDIM + kbase * 16 + lh * 8;
      #pragma unroll
      for (int i = 0; i < 4; i++)
        __builtin_amdgcn_global_load_lds((gas1_t)(gbase + i * 16),
                                         (las3_t)(&Ab[p ^ 1][(fbase + i) * 512]),
                                         16, 0, 0);
    }
    // prefetch node indices for tile t+2*NBLK (consumed next iteration)
    int nn2;
    {
      int tn = t + 2 * NBLK; if (tn >= NTILES) tn = NTILES - 1;
      int e1 = tn * 64 + smt * 32 + l31; if (e1 >= E_TOTAL) e1 = E_TOTAL - 1;
      nn2 = eptr[e1];
    }

    // ---- compute: 16 kt x (2 ds_read_b128 prefetch + 4 MFMA 32x32x16) ----
    f32x16 acc[2][2] = {};

    const unsigned short* Ap = &Ab[p][lane * 8];
    bf16x8 a0 = *(const bf16x8*)(Ap + (0 * 16 + 0) * 512);
    bf16x8 a1 = *(const bf16x8*)(Ap + (1 * 16 + 0) * 512);
    #pragma unroll
    for (int kt = 0; kt < 16; kt++) {
      bf16x8 na0 = a0, na1 = a1;
      if (kt < 15) {
        na0 = *(const bf16x8*)(Ap + (0 * 16 + kt + 1) * 512);
        na1 = *(const bf16x8*)(Ap + (1 * 16 + kt + 1) * 512);
      }
      acc[0][0] = __builtin_amdgcn_mfma_f32_32x32x16_bf16(a0, bq[0][kt], acc[0][0], 0, 0, 0);
      acc[1][0] = __builtin_amdgcn_mfma_f32_32x32x16_bf16(a1, bq[0][kt], acc[1][0], 0, 0, 0);
      acc[0][1] = __builtin_amdgcn_mfma_f32_32x32x16_bf16(a0, bq[1][kt], acc[0][1], 0, 0, 0);
      acc[1][1] = __builtin_amdgcn_mfma_f32_32x32x16_bf16(a1, bq[1][kt], acc[1][1], 0, 0, 0);
      a0 = na0; a1 = na1;
    }

    // ---- epilogue: relu(h+c)*w2, reduce over this wave's 64 cols ----
    // C/D 32x32 layout: col = lane&31, row = (reg&3) + 8*(reg>>2) + 4*(lane>>5)
    #pragma unroll
    for (int mt = 0; mt < 2; mt++) {
      #pragma unroll
      for (int r = 0; r < 16; r++) {
        float v = fmaxf(acc[mt][0][r] + cj[0], 0.f) * w2j[0]
                + fmaxf(acc[mt][1][r] + cj[1], 0.f) * w2j[1];
        v += __shfl_xor(v, 1);
        v += __shfl_xor(v, 2);
        v += __shfl_xor(v, 4);
        v += __shfl_xor(v, 8);
        v += __shfl_xor(v, 16);
        if (l31 == 0)
          partial[p][w][mt * 32 + (r & 3) + 8 * (r >> 2) + 4 * lh] = v;
      }
    }

    __syncthreads();   // drains next-tile DMA + publishes partial

    // ---- final combine + sigmoid (wave 0; waves 1-7 run ahead) ----
    if (tid < 64) {
      int e = t * 64 + tid;
      if (e < E_TOTAL) {
        float s = 0.f;
        #pragma unroll
        for (int ww = 0; ww < 8; ww++) s += partial[p][ww][tid];
        float logit = s + b2v;
        out[e] = 1.0f / (1.0f + __expf(-logit));
      }
    }
    nn = nn2;
    p ^= 1;
  }
}

extern "C" void kernel_launch(void* const* d_in, const int* in_sizes, int n_in,
                              void* d_out, int out_size, void* d_ws, size_t ws_size,
                              hipStream_t stream) {
  const float* node_feat = (const float*)d_in[0];
  const int*   eidx      = (const int*)d_in[1];
  const float* W1        = (const float*)d_in[2];
  const float* b1        = (const float*)d_in[3];
  const float* gamma     = (const float*)d_in[4];
  const float* beta      = (const float*)d_in[5];
  const float* mean      = (const float*)d_in[6];
  const float* var       = (const float*)d_in[7];
  const float* W2        = (const float*)d_in[8];
  const float* b2        = (const float*)d_in[9];
  float* out = (float*)d_out;

  // Workspace: Wswz bf16[512*256] (256KB) | cbias f32[512] | w2c f32[512] | nfb bf16[50000*128] (12.8MB)
  unsigned short* Wswz = (unsigned short*)d_ws;
  float* cbias = (float*)((char*)d_ws + (size_t)HDIM * KDIM * 2);
  float* w2c   = cbias + HDIM;
  unsigned short* nfb = (unsigned short*)(w2c + HDIM);

  prep_kernel<<<NF_BLOCKS + 17, 256, 0, stream>>>(node_feat, nfb, W1, b1, gamma, beta,
                                                  mean, var, W2, Wswz, cbias, w2c);

  edge_mlp_kernel<<<NBLK, 512, 0, stream>>>(nfb, eidx, Wswz, cbias, w2c, b2, out);
}

// Round 6
// 205.607 us; speedup vs baseline: 1.3009x; 1.3009x over previous
//
#include <hip/hip_runtime.h>
#include <hip/hip_bf16.h>

// Problem constants (from reference)
#define E_TOTAL 300000
#define N_NODES 50000
#define NDIM    128      // node feature dim
#define KDIM    256      // 2*NDIM = GEMM K
#define HDIM    512      // 2*HIDDEN = GEMM N (both MLP branches fused)
#define BN_EPS  1e-5f
#define NTILES  ((E_TOTAL + 63) / 64)   // 4688 tiles of 64 edges
#define NBLK    256                      // persistent blocks, 1/CU
#define NF_BLOCKS 6250                   // 50000*128/4 float4s / 256 threads
#define LT_MAX  19                       // max tiles per block

typedef __attribute__((ext_vector_type(8))) short bf16x8;
typedef __attribute__((ext_vector_type(4))) float f32x4;
typedef const __attribute__((address_space(1))) unsigned int* gas1_t;
typedef __attribute__((address_space(3))) unsigned int* las3_t;

__device__ __forceinline__ unsigned short f2bf(float f) {
  unsigned u = __float_as_uint(f);
  u += 0x7fffu + ((u >> 16) & 1u);   // round-to-nearest-even
  return (unsigned short)(u >> 16);
}

// ---- fused prep kernel ----
// blocks [0, NF_BLOCKS): node_feat fp32 -> bf16 table
// blocks [NF_BLOCKS, NF_BLOCKS+32): W1 (BN-folded, roll-fused) -> 16x16x32 B-frag order
//   frag (ct,kt), ct in [0,32), kt in [0,8): lane holds
//   B[k = kt*32 + (lane>>4)*8 + j][col = ct*16 + (lane&15)] at Wswz[((ct*8+kt)*64+lane)*8]
//   col>=256: roll branch uses W1[(k+16)&255].
// block NF_BLOCKS+32: folded bias (cbias) + 0.5*W2 (w2c)
__global__ void prep_kernel(const float* __restrict__ nf, unsigned short* __restrict__ nfb,
                            const float* __restrict__ W1, const float* __restrict__ b1,
                            const float* __restrict__ gamma, const float* __restrict__ beta,
                            const float* __restrict__ mean, const float* __restrict__ var,
                            const float* __restrict__ W2,
                            unsigned short* __restrict__ Wswz,
                            float* __restrict__ cbias, float* __restrict__ w2c) {
  int b = blockIdx.x;
  int tid = threadIdx.x;
  if (b < NF_BLOCKS) {
    int i = b * 256 + tid;                     // exactly 1.6M float4s
    float4 v = ((const float4*)nf)[i];
    ushort4 o;
    o.x = f2bf(v.x); o.y = f2bf(v.y); o.z = f2bf(v.z); o.w = f2bf(v.w);
    ((ushort4*)nfb)[i] = o;
  } else if (b < NF_BLOCKS + 32) {
    int ct   = b - NF_BLOCKS;                  // 0..31
    int lane = tid & 63;
    int col  = ct * 16 + (lane & 15);
    int quad = lane >> 4;
    int jj   = col & 255;
    int shift = (col >= 256) ? 16 : 0;
    float s = gamma[jj] * rsqrtf(var[jj] + BN_EPS);
    #pragma unroll
    for (int it = 0; it < 2; it++) {
      int kt = (tid >> 6) + it * 4;            // 0..7 across 256 threads x 2 iters
      unsigned short o[8];
      #pragma unroll
      for (int j = 0; j < 8; j++) {
        int k  = kt * 32 + quad * 8 + j;
        int ks = (k + shift) & 255;
        o[j] = f2bf(W1[ks * 256 + jj] * s);
      }
      *(uint4*)(Wswz + ((size_t)(ct * 8 + kt) * 64 + lane) * 8) = *(const uint4*)o;
    }
  } else {
    for (int j = tid; j < HDIM; j += 256) {
      int jj = j & 255;
      float s = gamma[jj] * rsqrtf(var[jj] + BN_EPS);
      cbias[j] = b1[jj] * s + beta[jj] - mean[jj] * s;
      w2c[j]  = 0.5f * W2[jj];                 // fold the 0.5 average here
    }
  }
}

// ---- main: persistent, 512 threads = 8 waves, 16x16x32 MFMA.
// Wave w owns cols [w*64, w*64+64); B in registers (bq[4][8] = 128 VGPR).
// 4-slot LDS ring for A tiles, DMA-staged (global_load_lds, line-coalesced),
// fine-grained s_waitcnt vmcnt(8) + raw s_barrier -> 3 tiles in flight.
// All edge indices preloaded to LDS (no vmem value-loads in the loop).
__global__ __launch_bounds__(512, 2) void edge_mlp_kernel(
    const unsigned short* __restrict__ nfb, const int* __restrict__ eidx,
    const unsigned short* __restrict__ Wswz, const float* __restrict__ cbias,
    const float* __restrict__ w2c, const float* __restrict__ b2,
    float* __restrict__ out) {
  __shared__ unsigned short Ab[4][32 * 512];   // 4 x 32KB = 128KB
  __shared__ int idxl[LT_MAX * 128];           // 9.5KB: [tile][half(2)][edge(64)]
  __shared__ float partial[2][8][64];          // 4KB, parity by tile

  const int tid  = threadIdx.x;
  const int w    = tid >> 6;
  const int lane = tid & 63;
  const int l16  = lane & 15;
  const int quad = lane >> 4;
  const int b    = blockIdx.x;
  const int ntl  = (NTILES - b + NBLK - 1) / NBLK;   // 18 or 19

  // ---- B into registers (once): wave w -> ct = w*4 .. w*4+3 ----
  const bf16x8* Wf = (const bf16x8*)Wswz;
  bf16x8 bq[4][8];
  #pragma unroll
  for (int n = 0; n < 4; n++)
    #pragma unroll
    for (int kt = 0; kt < 8; kt++)
      bq[n][kt] = Wf[((w * 4 + n) * 8 + kt) * 64 + lane];

  float cj[4], w2j[4];
  #pragma unroll
  for (int n = 0; n < 4; n++) {
    int j = w * 64 + n * 16 + l16;
    cj[n]  = cbias[j];
    w2j[n] = w2c[j];
  }
  const float b2v = b2[0];

  // ---- preload ALL this block's edge indices into LDS ----
  for (int g = tid; g < ntl * 128; g += 512) {
    int lt2 = g >> 7, r = g & 127;
    int half = r >> 6;
    int e = (b + lt2 * NBLK) * 64 + (r & 63);
    if (e >= E_TOTAL) e = E_TOTAL - 1;
    idxl[g] = eidx[half * E_TOTAL + e];
  }
  __syncthreads();   // prologue only: full drain is fine here

  // staging role (wave-constant): wave w stages frags (mt=w&3, kt=(w>>2)*4+i)
  const int smt   = w & 3;
  const int shalf = w >> 2;          // 0: row-node endpoint (k<128), 1: col-node
  const int sfrag0 = smt * 8 + shalf * 4;

  auto stage = [&](int lt2, int slot) {
    int node = idxl[lt2 * 128 + shalf * 64 + smt * 16 + l16];
    const unsigned short* gbase = nfb + (size_t)node * NDIM + quad * 8;
    // instr i: 4 same-edge lanes (quads) cover one contiguous 64B line
    #pragma unroll
    for (int i = 0; i < 4; i++)
      __builtin_amdgcn_global_load_lds((gas1_t)(gbase + i * 32),
                                       (las3_t)(&Ab[slot][(sfrag0 + i) * 512]),
                                       16, 0, 0);
  };

  // ---- prologue: stage slots 0,1,2 (12 DMAs outstanding) ----
  stage(0, 0);
  stage(1, 1);
  stage(2, 2);

  for (int lt = 0; lt < ntl; lt++) {
    // wait for OWN slot-lt DMAs only (oldest 4 of 12), then barrier
    __builtin_amdgcn_sched_barrier(0);
    __builtin_amdgcn_s_waitcnt(0x0078);   // vmcnt(8) lgkmcnt(0) expcnt(7)
    __builtin_amdgcn_s_barrier();
    __builtin_amdgcn_sched_barrier(0);

    // stage slot lt+3 into the ring slot freed last iteration (safe post-barrier)
    int ls = lt + 3; if (ls > ntl - 1) ls = ntl - 1;
    stage(ls, (lt + 3) & 3);

    // wave 0: combine previous tile's partials -> sigmoid -> store
    if (lt > 0 && tid < 64) {
      int e = (b + (lt - 1) * NBLK) * 64 + tid;
      if (e < E_TOTAL) {
        float s = 0.f;
        #pragma unroll
        for (int ww = 0; ww < 8; ww++) s += partial[(lt - 1) & 1][ww][tid];
        float logit = s + b2v;
        out[e] = 1.0f / (1.0f + __expf(-logit));
      }
    }

    // ---- compute slot lt: 8 kt x (4 ds_read_b128 + 16 MFMA) ----
    f32x4 acc[4][4] = {};
    const unsigned short* Ap = &Ab[lt & 3][lane * 8];
    #pragma unroll
    for (int kt = 0; kt < 8; kt++) {
      bf16x8 af[4];
      #pragma unroll
      for (int mt = 0; mt < 4; mt++)
        af[mt] = *(const bf16x8*)(Ap + (mt * 8 + kt) * 512);
      #pragma unroll
      for (int n = 0; n < 4; n++)
        #pragma unroll
        for (int mt = 0; mt < 4; mt++)
          acc[mt][n] = __builtin_amdgcn_mfma_f32_16x16x32_bf16(af[mt], bq[n][kt], acc[mt][n], 0, 0, 0);
    }

    // ---- epilogue: relu(h+c)*w2, reduce over this wave's 64 cols ----
    // C/D layout: col = lane&15, row = quad*4 + r
    #pragma unroll
    for (int mt = 0; mt < 4; mt++) {
      #pragma unroll
      for (int r = 0; r < 4; r++) {
        float v = 0.f;
        #pragma unroll
        for (int n = 0; n < 4; n++) {
          float h = acc[mt][n][r] + cj[n];
          v += fmaxf(h, 0.f) * w2j[n];
        }
        v += __shfl_xor(v, 1);
        v += __shfl_xor(v, 2);
        v += __shfl_xor(v, 4);
        v += __shfl_xor(v, 8);
        if (l16 == 0) partial[lt & 1][w][mt * 16 + quad * 4 + r] = v;
      }
    }
  }

  // ---- tail: combine last tile ----
  __builtin_amdgcn_sched_barrier(0);
  __builtin_amdgcn_s_waitcnt(0xC07F);     // lgkmcnt(0) only
  __builtin_amdgcn_s_barrier();
  __builtin_amdgcn_sched_barrier(0);
  if (tid < 64) {
    int e = (b + (ntl - 1) * NBLK) * 64 + tid;
    if (e < E_TOTAL) {
      float s = 0.f;
      #pragma unroll
      for (int ww = 0; ww < 8; ww++) s += partial[(ntl - 1) & 1][ww][tid];
      float logit = s + b2v;
      out[e] = 1.0f / (1.0f + __expf(-logit));
    }
  }
}

extern "C" void kernel_launch(void* const* d_in, const int* in_sizes, int n_in,
                              void* d_out, int out_size, void* d_ws, size_t ws_size,
                              hipStream_t stream) {
  const float* node_feat = (const float*)d_in[0];
  const int*   eidx      = (const int*)d_in[1];
  const float* W1        = (const float*)d_in[2];
  const float* b1        = (const float*)d_in[3];
  const float* gamma     = (const float*)d_in[4];
  const float* beta      = (const float*)d_in[5];
  const float* mean      = (const float*)d_in[6];
  const float* var       = (const float*)d_in[7];
  const float* W2        = (const float*)d_in[8];
  const float* b2        = (const float*)d_in[9];
  float* out = (float*)d_out;

  // Workspace: Wswz bf16[512*256] (256KB) | cbias f32[512] | w2c f32[512] | nfb bf16[50000*128] (12.8MB)
  unsigned short* Wswz = (unsigned short*)d_ws;
  float* cbias = (float*)((char*)d_ws + (size_t)HDIM * KDIM * 2);
  float* w2c   = cbias + HDIM;
  unsigned short* nfb = (unsigned short*)(w2c + HDIM);

  prep_kernel<<<NF_BLOCKS + 33, 256, 0, stream>>>(node_feat, nfb, W1, b1, gamma, beta,
                                                  mean, var, W2, Wswz, cbias, w2c);

  edge_mlp_kernel<<<NBLK, 512, 0, stream>>>(nfb, eidx, Wswz, cbias, w2c, b2, out);
}

// Round 7
// 174.772 us; speedup vs baseline: 1.5304x; 1.1764x over previous
//
#include <hip/hip_runtime.h>
#include <hip/hip_bf16.h>

// Problem constants (from reference)
#define E_TOTAL 300000
#define N_NODES 50000
#define NDIM    128      // node feature dim
#define KDIM    256      // 2*NDIM = GEMM K
#define HDIM    512      // 2*HIDDEN = GEMM N (both MLP branches fused)
#define BN_EPS  1e-5f
#define NTILES  ((E_TOTAL + 63) / 64)   // 4688 tiles of 64 edges
#define NBLK    256                      // persistent blocks, 1/CU
#define NF_BLOCKS 6250                   // 50000*128/4 float4s / 256 threads
#define LT_MAX  19                       // max tiles per block

typedef __attribute__((ext_vector_type(8))) short bf16x8;
typedef __attribute__((ext_vector_type(4))) float f32x4;
typedef const __attribute__((address_space(1))) unsigned int* gas1_t;
typedef __attribute__((address_space(3))) unsigned int* las3_t;

__device__ __forceinline__ unsigned short f2bf(float f) {
  unsigned u = __float_as_uint(f);
  u += 0x7fffu + ((u >> 16) & 1u);   // round-to-nearest-even
  return (unsigned short)(u >> 16);
}

// ---- fused prep kernel (unchanged from R6) ----
__global__ void prep_kernel(const float* __restrict__ nf, unsigned short* __restrict__ nfb,
                            const float* __restrict__ W1, const float* __restrict__ b1,
                            const float* __restrict__ gamma, const float* __restrict__ beta,
                            const float* __restrict__ mean, const float* __restrict__ var,
                            const float* __restrict__ W2,
                            unsigned short* __restrict__ Wswz,
                            float* __restrict__ cbias, float* __restrict__ w2c) {
  int b = blockIdx.x;
  int tid = threadIdx.x;
  if (b < NF_BLOCKS) {
    int i = b * 256 + tid;                     // exactly 1.6M float4s
    float4 v = ((const float4*)nf)[i];
    ushort4 o;
    o.x = f2bf(v.x); o.y = f2bf(v.y); o.z = f2bf(v.z); o.w = f2bf(v.w);
    ((ushort4*)nfb)[i] = o;
  } else if (b < NF_BLOCKS + 32) {
    int ct   = b - NF_BLOCKS;                  // 0..31
    int lane = tid & 63;
    int col  = ct * 16 + (lane & 15);
    int quad = lane >> 4;
    int jj   = col & 255;
    int shift = (col >= 256) ? 16 : 0;
    float s = gamma[jj] * rsqrtf(var[jj] + BN_EPS);
    #pragma unroll
    for (int it = 0; it < 2; it++) {
      int kt = (tid >> 6) + it * 4;            // 0..7
      unsigned short o[8];
      #pragma unroll
      for (int j = 0; j < 8; j++) {
        int k  = kt * 32 + quad * 8 + j;
        int ks = (k + shift) & 255;
        o[j] = f2bf(W1[ks * 256 + jj] * s);
      }
      *(uint4*)(Wswz + ((size_t)(ct * 8 + kt) * 64 + lane) * 8) = *(const uint4*)o;
    }
  } else {
    for (int j = tid; j < HDIM; j += 256) {
      int jj = j & 255;
      float s = gamma[jj] * rsqrtf(var[jj] + BN_EPS);
      cbias[j] = b1[jj] * s + beta[jj] - mean[jj] * s;
      w2c[j]  = 0.5f * W2[jj];                 // fold the 0.5 average
    }
  }
}

// ---- main: persistent, 512 threads = 8 waves, 16x16x32 MFMA.
// Wave w owns cols [w*64, w*64+64); B in registers (bq[4][8] = 128 VGPR).
// 4-slot LDS ring, DMA staging; ONE __syncthreads per TWO tiles -> between the
// pair's tiles waves drift, overlapping one wave's epilogue with another's MFMA.
__global__ __launch_bounds__(512, 2) void edge_mlp_kernel(
    const unsigned short* __restrict__ nfb, const int* __restrict__ eidx,
    const unsigned short* __restrict__ Wswz, const float* __restrict__ cbias,
    const float* __restrict__ w2c, const float* __restrict__ b2,
    float* __restrict__ out) {
  __shared__ unsigned short Ab[4][32 * 512];   // 128 KB
  __shared__ int idxl[LT_MAX * 128];           // 9.5 KB
  __shared__ float partial[4][8][64];          // 8 KB, ring by tile&3

  const int tid  = threadIdx.x;
  const int w    = tid >> 6;
  const int lane = tid & 63;
  const int l16  = lane & 15;
  const int quad = lane >> 4;
  const int b    = blockIdx.x;
  const int ntl  = (NTILES - b + NBLK - 1) / NBLK;   // 18 or 19

  // ---- B into registers (once): wave w -> ct = w*4 .. w*4+3 ----
  const bf16x8* Wf = (const bf16x8*)Wswz;
  bf16x8 bq[4][8];
  #pragma unroll
  for (int n = 0; n < 4; n++)
    #pragma unroll
    for (int kt = 0; kt < 8; kt++)
      bq[n][kt] = Wf[((w * 4 + n) * 8 + kt) * 64 + lane];

  float cj[4], w2j[4];
  #pragma unroll
  for (int n = 0; n < 4; n++) {
    int j = w * 64 + n * 16 + l16;
    cj[n]  = cbias[j];
    w2j[n] = w2c[j];
  }
  const float b2v = b2[0];

  // ---- preload ALL this block's edge indices into LDS ----
  for (int g = tid; g < ntl * 128; g += 512) {
    int lt2 = g >> 7, r = g & 127;
    int half = r >> 6;
    int e = (b + lt2 * NBLK) * 64 + (r & 63);
    if (e >= E_TOTAL) e = E_TOTAL - 1;
    idxl[g] = eidx[half * E_TOTAL + e];
  }
  __syncthreads();

  // staging role (wave-constant): wave w stages frags f = sfrag0+i, i=0..3
  const int smt    = w & 3;
  const int shalf  = w >> 2;         // 0: row-node endpoint (k<128), 1: col-node
  const int sfrag0 = smt * 8 + shalf * 4;

  auto stage = [&](int lt2, int slot) {
    int node = idxl[lt2 * 128 + shalf * 64 + smt * 16 + l16];
    const unsigned short* gbase = nfb + (size_t)node * NDIM + quad * 8;
    // instr i: 4 same-edge lanes (quads) cover one contiguous 64B line
    #pragma unroll
    for (int i = 0; i < 4; i++)
      __builtin_amdgcn_global_load_lds((gas1_t)(gbase + i * 32),
                                       (las3_t)(&Ab[slot][(sfrag0 + i) * 512]),
                                       16, 0, 0);
  };

  auto combine = [&](int lt2, int le) {
    int e = (b + lt2 * NBLK) * 64 + le;
    if (e < E_TOTAL) {
      float s = 0.f;
      #pragma unroll
      for (int ww = 0; ww < 8; ww++) s += partial[lt2 & 3][ww][le];
      out[e] = 1.0f / (1.0f + __expf(-(s + b2v)));
    }
  };

  auto compute_tile = [&](int lt2) {
    f32x4 acc[4][4] = {};
    const unsigned short* Ap = &Ab[lt2 & 3][lane * 8];
    #pragma unroll
    for (int kt = 0; kt < 8; kt++) {
      bf16x8 af[4];
      #pragma unroll
      for (int mt = 0; mt < 4; mt++)
        af[mt] = *(const bf16x8*)(Ap + (mt * 8 + kt) * 512);
      #pragma unroll
      for (int n = 0; n < 4; n++)
        #pragma unroll
        for (int mt = 0; mt < 4; mt++)
          acc[mt][n] = __builtin_amdgcn_mfma_f32_16x16x32_bf16(af[mt], bq[n][kt], acc[mt][n], 0, 0, 0);
    }

    // epilogue: relu(h+c)*w2 summed over my 4 col-tiles -> 16 independent values
    float vs[16];
    #pragma unroll
    for (int mt = 0; mt < 4; mt++)
      #pragma unroll
      for (int r = 0; r < 4; r++) {
        float v = 0.f;
        #pragma unroll
        for (int n = 0; n < 4; n++) {
          float h = acc[mt][n][r] + cj[n];
          v += fmaxf(h, 0.f) * w2j[n];
        }
        vs[mt * 4 + r] = v;
      }
    // stage-batched 16-lane reduction: 16-wide ILP per stage (no serial chains)
    #pragma unroll
    for (int s = 1; s < 16; s <<= 1) {
      float t[16];
      #pragma unroll
      for (int i = 0; i < 16; i++) t[i] = __shfl_xor(vs[i], s);
      #pragma unroll
      for (int i = 0; i < 16; i++) vs[i] += t[i];
    }
    if (l16 == 0) {
      #pragma unroll
      for (int mt = 0; mt < 4; mt++)
        #pragma unroll
        for (int r = 0; r < 4; r++)
          partial[lt2 & 3][w][mt * 16 + quad * 4 + r] = vs[mt * 4 + r];
    }
  };

  // ---- prologue: stage tiles 0,1 ----
  stage(0, 0);
  if (1 < ntl) stage(1, 1);

  // ---- main loop: one barrier per PAIR of tiles ----
  for (int lt = 0; lt < ntl; lt += 2) {
    __syncthreads();   // drains own DMAs (issued a full pair ago), syncs partial ring

    int s2 = lt + 2, s3 = lt + 3;
    if (s2 < ntl) stage(s2, s2 & 3);
    if (s3 < ntl) stage(s3, s3 & 3);

    if (lt >= 2) {
      if (tid < 64)       combine(lt - 2, tid);
      else if (tid < 128) combine(lt - 1, tid - 64);
    }

    compute_tile(lt);
    if (lt + 1 < ntl) compute_tile(lt + 1);
  }

  // ---- tail: combine the last pair ----
  __syncthreads();
  if ((ntl & 1) == 0) {
    if (tid < 64)       combine(ntl - 2, tid);
    else if (tid < 128) combine(ntl - 1, tid - 64);
  } else {
    if (tid < 64)       combine(ntl - 1, tid);
  }
}

extern "C" void kernel_launch(void* const* d_in, const int* in_sizes, int n_in,
                              void* d_out, int out_size, void* d_ws, size_t ws_size,
                              hipStream_t stream) {
  const float* node_feat = (const float*)d_in[0];
  const int*   eidx      = (const int*)d_in[1];
  const float* W1        = (const float*)d_in[2];
  const float* b1        = (const float*)d_in[3];
  const float* gamma     = (const float*)d_in[4];
  const float* beta      = (const float*)d_in[5];
  const float* mean      = (const float*)d_in[6];
  const float* var       = (const float*)d_in[7];
  const float* W2        = (const float*)d_in[8];
  const float* b2        = (const float*)d_in[9];
  float* out = (float*)d_out;

  // Workspace: Wswz bf16[512*256] (256KB) | cbias f32[512] | w2c f32[512] | nfb bf16[50000*128] (12.8MB)
  unsigned short* Wswz = (unsigned short*)d_ws;
  float* cbias = (float*)((char*)d_ws + (size_t)HDIM * KDIM * 2);
  float* w2c   = cbias + HDIM;
  unsigned short* nfb = (unsigned short*)(w2c + HDIM);

  prep_kernel<<<NF_BLOCKS + 33, 256, 0, stream>>>(node_feat, nfb, W1, b1, gamma, beta,
                                                  mean, var, W2, Wswz, cbias, w2c);

  edge_mlp_kernel<<<NBLK, 512, 0, stream>>>(nfb, eidx, Wswz, cbias, w2c, b2, out);
}

// Round 8
// 167.403 us; speedup vs baseline: 1.5978x; 1.0440x over previous
//
#include <hip/hip_runtime.h>
#include <hip/hip_bf16.h>

// Problem constants (from reference)
#define E_TOTAL 300000
#define N_NODES 50000
#define NDIM    128      // node feature dim
#define KDIM    256      // 2*NDIM = GEMM K
#define HDIM    512      // 2*HIDDEN = GEMM N (both MLP branches fused)
#define BN_EPS  1e-5f
#define NTILES  ((E_TOTAL + 63) / 64)   // 4688 tiles of 64 edges
#define NBLK    256                      // persistent blocks, 1/CU
#define NF_BLOCKS 6250                   // 50000*128/4 float4s / 256 threads
#define LT_MAX  19                       // max tiles per block

typedef __attribute__((ext_vector_type(8))) short bf16x8;
typedef __attribute__((ext_vector_type(4))) float f32x4;
typedef const __attribute__((address_space(1))) unsigned int* gas1_t;
typedef __attribute__((address_space(3))) unsigned int* las3_t;

__device__ __forceinline__ unsigned short f2bf(float f) {
  unsigned u = __float_as_uint(f);
  u += 0x7fffu + ((u >> 16) & 1u);   // round-to-nearest-even
  return (unsigned short)(u >> 16);
}

// DPP rotate-add stage over all 16 partials (VALU pipe, zero LDS traffic).
// row_ror:N ctrl = 0x120|N; rows are 16 lanes, exactly our reduction group.
#define DPP_STAGE(C)                                                          \
  {                                                                           \
    _Pragma("unroll")                                                         \
    for (int i = 0; i < 16; i++) {                                            \
      int t = __builtin_amdgcn_update_dpp(0, __float_as_int(vs[i]),           \
                                          (C), 0xF, 0xF, true);               \
      vs[i] += __int_as_float(t);                                             \
    }                                                                         \
  }

// ---- fused prep kernel (unchanged from R7) ----
__global__ void prep_kernel(const float* __restrict__ nf, unsigned short* __restrict__ nfb,
                            const float* __restrict__ W1, const float* __restrict__ b1,
                            const float* __restrict__ gamma, const float* __restrict__ beta,
                            const float* __restrict__ mean, const float* __restrict__ var,
                            const float* __restrict__ W2,
                            unsigned short* __restrict__ Wswz,
                            float* __restrict__ cbias, float* __restrict__ w2c) {
  int b = blockIdx.x;
  int tid = threadIdx.x;
  if (b < NF_BLOCKS) {
    int i = b * 256 + tid;                     // exactly 1.6M float4s
    float4 v = ((const float4*)nf)[i];
    ushort4 o;
    o.x = f2bf(v.x); o.y = f2bf(v.y); o.z = f2bf(v.z); o.w = f2bf(v.w);
    ((ushort4*)nfb)[i] = o;
  } else if (b < NF_BLOCKS + 32) {
    int ct   = b - NF_BLOCKS;                  // 0..31
    int lane = tid & 63;
    int col  = ct * 16 + (lane & 15);
    int quad = lane >> 4;
    int jj   = col & 255;
    int shift = (col >= 256) ? 16 : 0;
    float s = gamma[jj] * rsqrtf(var[jj] + BN_EPS);
    #pragma unroll
    for (int it = 0; it < 2; it++) {
      int kt = (tid >> 6) + it * 4;            // 0..7
      unsigned short o[8];
      #pragma unroll
      for (int j = 0; j < 8; j++) {
        int k  = kt * 32 + quad * 8 + j;
        int ks = (k + shift) & 255;
        o[j] = f2bf(W1[ks * 256 + jj] * s);
      }
      *(uint4*)(Wswz + ((size_t)(ct * 8 + kt) * 64 + lane) * 8) = *(const uint4*)o;
    }
  } else {
    for (int j = tid; j < HDIM; j += 256) {
      int jj = j & 255;
      float s = gamma[jj] * rsqrtf(var[jj] + BN_EPS);
      cbias[j] = b1[jj] * s + beta[jj] - mean[jj] * s;
      w2c[j]  = 0.5f * W2[jj];                 // fold the 0.5 average
    }
  }
}

// ---- main: persistent, 512 threads = 8 waves, 16x16x32 MFMA.
// Wave w owns cols [w*64, w*64+64); B in registers (bq[4][8] = 128 VGPR).
// 4-slot LDS ring, DMA staging; ONE __syncthreads per TWO tiles (waves drift
// within the pair). Epilogue reduction via DPP row_ror (VALU pipe, no LDS).
__global__ __launch_bounds__(512, 2) void edge_mlp_kernel(
    const unsigned short* __restrict__ nfb, const int* __restrict__ eidx,
    const unsigned short* __restrict__ Wswz, const float* __restrict__ cbias,
    const float* __restrict__ w2c, const float* __restrict__ b2,
    float* __restrict__ out) {
  __shared__ unsigned short Ab[4][32 * 512];   // 128 KB
  __shared__ int idxl[LT_MAX * 128];           // 9.5 KB
  __shared__ float partial[4][8][64];          // 8 KB, ring by tile&3

  const int tid  = threadIdx.x;
  const int w    = tid >> 6;
  const int lane = tid & 63;
  const int l16  = lane & 15;
  const int quad = lane >> 4;
  const int b    = blockIdx.x;
  const int ntl  = (NTILES - b + NBLK - 1) / NBLK;   // 18 or 19

  // ---- B into registers (once): wave w -> ct = w*4 .. w*4+3 ----
  const bf16x8* Wf = (const bf16x8*)Wswz;
  bf16x8 bq[4][8];
  #pragma unroll
  for (int n = 0; n < 4; n++)
    #pragma unroll
    for (int kt = 0; kt < 8; kt++)
      bq[n][kt] = Wf[((w * 4 + n) * 8 + kt) * 64 + lane];

  float cj[4], w2j[4];
  #pragma unroll
  for (int n = 0; n < 4; n++) {
    int j = w * 64 + n * 16 + l16;
    cj[n]  = cbias[j];
    w2j[n] = w2c[j];
  }
  const float b2v = b2[0];

  // ---- preload ALL this block's edge indices into LDS ----
  for (int g = tid; g < ntl * 128; g += 512) {
    int lt2 = g >> 7, r = g & 127;
    int half = r >> 6;
    int e = (b + lt2 * NBLK) * 64 + (r & 63);
    if (e >= E_TOTAL) e = E_TOTAL - 1;
    idxl[g] = eidx[half * E_TOTAL + e];
  }
  __syncthreads();

  // staging role (wave-constant): wave w stages frags f = sfrag0+i, i=0..3
  const int smt    = w & 3;
  const int shalf  = w >> 2;         // 0: row-node endpoint (k<128), 1: col-node
  const int sfrag0 = smt * 8 + shalf * 4;

  auto stage = [&](int lt2, int slot) {
    int node = idxl[lt2 * 128 + shalf * 64 + smt * 16 + l16];
    const unsigned short* gbase = nfb + (size_t)node * NDIM + quad * 8;
    // instr i: 4 same-edge lanes (quads) cover one contiguous 64B line
    #pragma unroll
    for (int i = 0; i < 4; i++)
      __builtin_amdgcn_global_load_lds((gas1_t)(gbase + i * 32),
                                       (las3_t)(&Ab[slot][(sfrag0 + i) * 512]),
                                       16, 0, 0);
  };

  auto combine = [&](int lt2, int le) {
    int e = (b + lt2 * NBLK) * 64 + le;
    if (e < E_TOTAL) {
      float s = 0.f;
      #pragma unroll
      for (int ww = 0; ww < 8; ww++) s += partial[lt2 & 3][ww][le];
      out[e] = 1.0f / (1.0f + __expf(-(s + b2v)));
    }
  };

  auto compute_tile = [&](int lt2) {
    f32x4 acc[4][4] = {};
    const unsigned short* Ap = &Ab[lt2 & 3][lane * 8];
    #pragma unroll
    for (int kt = 0; kt < 8; kt++) {
      bf16x8 af[4];
      #pragma unroll
      for (int mt = 0; mt < 4; mt++)
        af[mt] = *(const bf16x8*)(Ap + (mt * 8 + kt) * 512);
      #pragma unroll
      for (int n = 0; n < 4; n++)
        #pragma unroll
        for (int mt = 0; mt < 4; mt++)
          acc[mt][n] = __builtin_amdgcn_mfma_f32_16x16x32_bf16(af[mt], bq[n][kt], acc[mt][n], 0, 0, 0);
    }

    // epilogue: relu(h+c)*w2 summed over my 4 col-tiles -> 16 independent values
    float vs[16];
    #pragma unroll
    for (int mt = 0; mt < 4; mt++)
      #pragma unroll
      for (int r = 0; r < 4; r++) {
        float v = 0.f;
        #pragma unroll
        for (int n = 0; n < 4; n++) {
          float h = acc[mt][n][r] + cj[n];
          v += fmaxf(h, 0.f) * w2j[n];
        }
        vs[mt * 4 + r] = v;
      }
    // 16-lane rotate-butterfly on the VALU pipe (DPP row_ror), 16-wide ILP/stage
    DPP_STAGE(0x128)   // ror 8
    DPP_STAGE(0x124)   // ror 4
    DPP_STAGE(0x122)   // ror 2
    DPP_STAGE(0x121)   // ror 1
    if (l16 == 0) {
      #pragma unroll
      for (int mt = 0; mt < 4; mt++)
        #pragma unroll
        for (int r = 0; r < 4; r++)
          partial[lt2 & 3][w][mt * 16 + quad * 4 + r] = vs[mt * 4 + r];
    }
  };

  // ---- prologue: stage tiles 0,1 ----
  stage(0, 0);
  if (1 < ntl) stage(1, 1);

  // ---- main loop: one barrier per PAIR of tiles ----
  for (int lt = 0; lt < ntl; lt += 2) {
    __syncthreads();   // drains own DMAs (issued a full pair ago), syncs partial ring

    int s2 = lt + 2, s3 = lt + 3;
    if (s2 < ntl) stage(s2, s2 & 3);
    if (s3 < ntl) stage(s3, s3 & 3);

    if (lt >= 2) {
      if (tid < 64)       combine(lt - 2, tid);
      else if (tid < 128) combine(lt - 1, tid - 64);
    }

    compute_tile(lt);
    if (lt + 1 < ntl) compute_tile(lt + 1);
  }

  // ---- tail: combine the last pair ----
  __syncthreads();
  if ((ntl & 1) == 0) {
    if (tid < 64)       combine(ntl - 2, tid);
    else if (tid < 128) combine(ntl - 1, tid - 64);
  } else {
    if (tid < 64)       combine(ntl - 1, tid);
  }
}

extern "C" void kernel_launch(void* const* d_in, const int* in_sizes, int n_in,
                              void* d_out, int out_size, void* d_ws, size_t ws_size,
                              hipStream_t stream) {
  const float* node_feat = (const float*)d_in[0];
  const int*   eidx      = (const int*)d_in[1];
  const float* W1        = (const float*)d_in[2];
  const float* b1        = (const float*)d_in[3];
  const float* gamma     = (const float*)d_in[4];
  const float* beta      = (const float*)d_in[5];
  const float* mean      = (const float*)d_in[6];
  const float* var       = (const float*)d_in[7];
  const float* W2        = (const float*)d_in[8];
  const float* b2        = (const float*)d_in[9];
  float* out = (float*)d_out;

  // Workspace: Wswz bf16[512*256] (256KB) | cbias f32[512] | w2c f32[512] | nfb bf16[50000*128] (12.8MB)
  unsigned short* Wswz = (unsigned short*)d_ws;
  float* cbias = (float*)((char*)d_ws + (size_t)HDIM * KDIM * 2);
  float* w2c   = cbias + HDIM;
  unsigned short* nfb = (unsigned short*)(w2c + HDIM);

  prep_kernel<<<NF_BLOCKS + 33, 256, 0, stream>>>(node_feat, nfb, W1, b1, gamma, beta,
                                                  mean, var, W2, Wswz, cbias, w2c);

  edge_mlp_kernel<<<NBLK, 512, 0, stream>>>(nfb, eidx, Wswz, cbias, w2c, b2, out);
}